// Round 1
// baseline (35.369 us; speedup 1.0000x reference)
//
#include <hip/hip_runtime.h>
#include <stdint.h>

#define NB 64      // batch rows
#define NK 1024    // keys
#define ND 512     // dim
#define CHUNKS 16
#define KEYS_PER_BLOCK (NK / CHUNKS)                    // 64
#define WAVES_PER_BLOCK 4
#define KEYS_PER_WAVE (KEYS_PER_BLOCK / WAVES_PER_BLOCK) // 16

#if __has_builtin(__builtin_amdgcn_exp2f)
#define EXP2F(x) __builtin_amdgcn_exp2f(x)
#else
#define EXP2F(x) exp2f(x)
#endif
#if __has_builtin(__builtin_amdgcn_rcpf)
#define RCPF(x) __builtin_amdgcn_rcpf(x)
#else
#define RCPF(x) (1.0f / (x))
#endif

// silu term with gate b=1 on active dims; inactive key elems are zeroed so the
// term is exactly 0 (matches reference's active-mask multiply).
__device__ __forceinline__ float silu_term(float qc, float kv) {
    // zero inactive key element: contribution becomes 0*sigmoid(1) = 0
    float kz = (fabsf(kv) > 1e-6f) ? kv : 0.0f;
    float u = qc * kz;
    // sigmoid(u+1) = 1/(1 + exp(-(u+1))) = 1/(1 + exp2(-(u+1)*log2e))
    const float NL2E = -1.4426950408889634f;
    float y = fmaf(u, NL2E, NL2E);          // -(u+1)*log2e
    float e = EXP2F(y);
    float r = RCPF(1.0f + e);
    return u * r;
}

__global__ __launch_bounds__(256) void sia_scores(const float* __restrict__ q,
                                                  const float* __restrict__ keys,
                                                  unsigned long long* __restrict__ best) {
    const int bidx = blockIdx.x;            // 0 .. NB*CHUNKS-1
    const int b = bidx >> 4;                // / CHUNKS
    const int chunk = bidx & (CHUNKS - 1);
    const int tid = threadIdx.x;
    const int wave = tid >> 6;
    const int lane = tid & 63;

    // C = SCALE * D^-0.5 = 100/sqrt(512)
    const float C = 100.0f * 0.04419417382415922f;

    // each lane owns 8 consecutive dims: [lane*8, lane*8+8)
    const float4* q4 = reinterpret_cast<const float4*>(q + b * ND + lane * 8);
    float4 qa = q4[0];
    float4 qb = q4[1];
    qa.x *= C; qa.y *= C; qa.z *= C; qa.w *= C;
    qb.x *= C; qb.y *= C; qb.z *= C; qb.w *= C;

    float best_s = -3.0e38f;
    int best_k = 0;

    const int k0 = chunk * KEYS_PER_BLOCK + wave * KEYS_PER_WAVE;
    for (int i = 0; i < KEYS_PER_WAVE; ++i) {
        const int k = k0 + i;
        const float4* k4 = reinterpret_cast<const float4*>(keys + k * ND + lane * 8);
        float4 ka = k4[0];
        float4 kb = k4[1];

        float p = 0.0f;
        p += silu_term(qa.x, ka.x);
        p += silu_term(qa.y, ka.y);
        p += silu_term(qa.z, ka.z);
        p += silu_term(qa.w, ka.w);
        p += silu_term(qb.x, kb.x);
        p += silu_term(qb.y, kb.y);
        p += silu_term(qb.z, kb.z);
        p += silu_term(qb.w, kb.w);

        // butterfly reduce across the 64-lane wave
        #pragma unroll
        for (int off = 32; off > 0; off >>= 1)
            p += __shfl_xor(p, off, 64);

        // strict > keeps the earliest key on exact ties (numpy argmax semantics)
        if (p > best_s) { best_s = p; best_k = k; }
    }

    if (lane == 0) {
        // sortable-uint encoding of float: monotone order-preserving
        uint32_t bits = __float_as_uint(best_s);
        uint32_t s = (bits & 0x80000000u) ? ~bits : (bits | 0x80000000u);
        // low word ~idx: on score ties, smaller idx wins (larger low word)
        unsigned long long packed =
            ((unsigned long long)s << 32) | (unsigned long long)(~(uint32_t)best_k);
        atomicMax(&best[b], packed);
    }
}

__global__ __launch_bounds__(128) void sia_gather(const unsigned long long* __restrict__ best,
                                                  const float* __restrict__ values,
                                                  float* __restrict__ out) {
    const int b = blockIdx.x;
    const unsigned long long p = best[b];
    const uint32_t k = ~(uint32_t)(p & 0xFFFFFFFFull);

    const float4* v4 = reinterpret_cast<const float4*>(values + (size_t)k * ND);
    float4* o4 = reinterpret_cast<float4*>(out + b * ND);
    o4[threadIdx.x] = v4[threadIdx.x];   // 128 threads x 16B = 2KB row

    if (threadIdx.x == 0) {
        // winner_idx output: harness reads d_out as float32
        out[NB * ND + b] = (float)k;
    }
}

extern "C" void kernel_launch(void* const* d_in, const int* in_sizes, int n_in,
                              void* d_out, int out_size, void* d_ws, size_t ws_size,
                              hipStream_t stream) {
    const float* q      = (const float*)d_in[0];   // [64, 512]
    const float* keys   = (const float*)d_in[1];   // [1024, 512]
    const float* values = (const float*)d_in[2];   // [1024, 512]
    float* out = (float*)d_out;                    // 64*512 values then 64 idx
    unsigned long long* best = (unsigned long long*)d_ws;

    hipMemsetAsync(d_ws, 0, NB * sizeof(unsigned long long), stream);
    sia_scores<<<dim3(NB * CHUNKS), dim3(256), 0, stream>>>(q, keys, best);
    sia_gather<<<dim3(NB), dim3(128), 0, stream>>>(best, values, out);
}

// Round 2
// 19.311 us; speedup vs baseline: 1.8316x; 1.8316x over previous
//
#include <hip/hip_runtime.h>
#include <stdint.h>

#define NB 64      // batch rows
#define NK 1024    // keys
#define ND 512     // dim
#define CHUNKS 16
#define KEYS_PER_BLOCK (NK / CHUNKS)                     // 64
#define WAVES_PER_BLOCK 4
#define KEYS_PER_WAVE (KEYS_PER_BLOCK / WAVES_PER_BLOCK) // 16
// ws layout: u64 packed winner per (row, wave-slot): [NB][64]

#if __has_builtin(__builtin_amdgcn_exp2f)
#define EXP2F(x) __builtin_amdgcn_exp2f(x)
#else
#define EXP2F(x) exp2f(x)
#endif
#if __has_builtin(__builtin_amdgcn_rcpf)
#define RCPF(x) __builtin_amdgcn_rcpf(x)
#else
#define RCPF(x) (1.0f / (x))
#endif

// silu term with gate b=1 on active dims; inactive key elems are zeroed so the
// term is exactly 0 (matches reference's active-mask multiply).
__device__ __forceinline__ float silu_term(float qc, float kv, float acc) {
    float kz = (fabsf(kv) > 1e-6f) ? kv : 0.0f;
    float u = qc * kz;
    // sigmoid(u+1) = 1/(1 + exp2(-(u+1)*log2e))
    const float NL2E = -1.4426950408889634f;
    float y = fmaf(u, NL2E, NL2E);
    float e = EXP2F(y);
    float r = RCPF(1.0f + e);
    return fmaf(u, r, acc);
}

__device__ __forceinline__ unsigned long long pack_win(float s, int k) {
    uint32_t bits = __float_as_uint(s);
    uint32_t so = (bits & 0x80000000u) ? ~bits : (bits | 0x80000000u);
    // low word = ~k: on score ties the SMALLER key index wins under max()
    return ((unsigned long long)so << 32) | (unsigned long long)(~(uint32_t)k);
}

__global__ __launch_bounds__(256) void sia_scores(const float* __restrict__ q,
                                                  const float* __restrict__ keys,
                                                  unsigned long long* __restrict__ ws) {
    const int bidx = blockIdx.x;            // 0 .. NB*CHUNKS-1
    const int b = bidx >> 4;                // / CHUNKS
    const int chunk = bidx & (CHUNKS - 1);
    const int tid = threadIdx.x;
    const int wave = tid >> 6;
    const int lane = tid & 63;

    const float C = 100.0f * 0.04419417382415922f;   // SCALE * D^-0.5

    // each lane owns 8 consecutive dims
    const float4* q4 = reinterpret_cast<const float4*>(q + b * ND + lane * 8);
    float4 qa = q4[0];
    float4 qb = q4[1];
    qa.x *= C; qa.y *= C; qa.z *= C; qa.w *= C;
    qb.x *= C; qb.y *= C; qb.z *= C; qb.w *= C;

    const int k0 = chunk * KEYS_PER_BLOCK + wave * KEYS_PER_WAVE;

    // Phase 1: pure compute, no cross-lane ops — 16 per-lane partials.
    float acc[KEYS_PER_WAVE];
    #pragma unroll
    for (int i = 0; i < KEYS_PER_WAVE; ++i) {
        const float4* k4 = reinterpret_cast<const float4*>(keys + (k0 + i) * ND + lane * 8);
        float4 ka = k4[0];
        float4 kb = k4[1];
        float p = 0.0f;
        p = silu_term(qa.x, ka.x, p);
        p = silu_term(qa.y, ka.y, p);
        p = silu_term(qa.z, ka.z, p);
        p = silu_term(qa.w, ka.w, p);
        p = silu_term(qb.x, kb.x, p);
        p = silu_term(qb.y, kb.y, p);
        p = silu_term(qb.z, kb.z, p);
        p = silu_term(qb.w, kb.w, p);
        acc[i] = p;
    }

    // Phase 2: batched butterfly — 96 independent shfl+add, latency overlaps.
    #pragma unroll
    for (int off = 32; off > 0; off >>= 1) {
        #pragma unroll
        for (int i = 0; i < KEYS_PER_WAVE; ++i)
            acc[i] += __shfl_xor(acc[i], off, 64);
    }

    // Per-wave argmax over its 16 keys (every lane has all sums; redundant).
    float best_s = acc[0];
    int best_j = 0;
    #pragma unroll
    for (int i = 1; i < KEYS_PER_WAVE; ++i)
        if (acc[i] > best_s) { best_s = acc[i]; best_j = i; }   // strict >: earliest wins

    if (lane == 0)
        ws[b * 64 + chunk * WAVES_PER_BLOCK + wave] = pack_win(best_s, k0 + best_j);
}

__global__ __launch_bounds__(64) void sia_final(const unsigned long long* __restrict__ ws,
                                                const float* __restrict__ values,
                                                float* __restrict__ out) {
    const int b = blockIdx.x;
    const int lane = threadIdx.x;

    unsigned long long p = ws[b * 64 + lane];
    #pragma unroll
    for (int off = 32; off > 0; off >>= 1) {
        unsigned long long o = __shfl_xor(p, off, 64);
        if (o > p) p = o;
    }
    const uint32_t k = ~(uint32_t)(p & 0xFFFFFFFFull);

    // gather winner's values row: 64 lanes x 8 floats
    const float4* v4 = reinterpret_cast<const float4*>(values + (size_t)k * ND) + lane * 2;
    float4* o4 = reinterpret_cast<float4*>(out + b * ND) + lane * 2;
    o4[0] = v4[0];
    o4[1] = v4[1];

    if (lane == 0)
        out[NB * ND + b] = (float)k;   // winner_idx, read back as float32
}

extern "C" void kernel_launch(void* const* d_in, const int* in_sizes, int n_in,
                              void* d_out, int out_size, void* d_ws, size_t ws_size,
                              hipStream_t stream) {
    const float* q      = (const float*)d_in[0];   // [64, 512]
    const float* keys   = (const float*)d_in[1];   // [1024, 512]
    const float* values = (const float*)d_in[2];   // [1024, 512]
    float* out = (float*)d_out;                    // 64*512 values then 64 idx
    unsigned long long* ws = (unsigned long long*)d_ws;

    sia_scores<<<dim3(NB * CHUNKS), dim3(256), 0, stream>>>(q, keys, ws);
    sia_final<<<dim3(NB), dim3(64), 0, stream>>>(ws, values, out);
}

// Round 3
// 17.915 us; speedup vs baseline: 1.9743x; 1.0779x over previous
//
#include <hip/hip_runtime.h>
#include <stdint.h>

#define NB 64      // batch rows
#define NK 1024    // keys
#define ND 512     // dim
#define ROWS 4                                  // batch rows per block
#define CHUNKS 64                               // key chunks
#define KEYS_PER_BLOCK (NK / CHUNKS)            // 16
#define WAVES_PER_BLOCK 4
#define KEYS_PER_WAVE (KEYS_PER_BLOCK / WAVES_PER_BLOCK)  // 4
// ws layout: u64 packed winner per (row, chunk): [NB][CHUNKS]

#if __has_builtin(__builtin_amdgcn_exp2f)
#define EXP2F(x) __builtin_amdgcn_exp2f(x)
#else
#define EXP2F(x) exp2f(x)
#endif
#if __has_builtin(__builtin_amdgcn_rcpf)
#define RCPF(x) __builtin_amdgcn_rcpf(x)
#else
#define RCPF(x) (1.0f / (x))
#endif

// u * sigmoid(u + 1) accumulated into acc; key element pre-masked.
__device__ __forceinline__ float silu_acc(float qc, float kz, float acc) {
    float u = qc * kz;
    const float NL2E = -1.4426950408889634f;
    float y = fmaf(u, NL2E, NL2E);      // -(u+1)*log2e
    float e = EXP2F(y);
    float r = RCPF(1.0f + e);
    return fmaf(u, r, acc);
}

__device__ __forceinline__ unsigned long long pack_win(float s, int k) {
    uint32_t bits = __float_as_uint(s);
    uint32_t so = (bits & 0x80000000u) ? ~bits : (bits | 0x80000000u);
    // low word = ~k: on score ties the SMALLER key index wins under max()
    return ((unsigned long long)so << 32) | (unsigned long long)(~(uint32_t)k);
}

__device__ __forceinline__ float msk(float kv) {
    return (fabsf(kv) > 1e-6f) ? kv : 0.0f;
}

__global__ __launch_bounds__(256) void sia_scores(const float* __restrict__ q,
                                                  const float* __restrict__ keys,
                                                  unsigned long long* __restrict__ ws) {
    const int bidx = blockIdx.x;            // 0 .. NB/ROWS*CHUNKS-1 = 1023
    const int bg = bidx >> 6;               // row group 0..15
    const int chunk = bidx & (CHUNKS - 1);  // 0..63
    const int tid = threadIdx.x;
    const int wave = tid >> 6;
    const int lane = tid & 63;

    const float C = 100.0f * 0.04419417382415922f;   // SCALE * D^-0.5

    // 4 rows' q fragments, each lane owns dims [lane*8, lane*8+8)
    float4 qa[ROWS], qb[ROWS];
    #pragma unroll
    for (int r = 0; r < ROWS; ++r) {
        const float4* q4 = reinterpret_cast<const float4*>(q + (bg * ROWS + r) * ND + lane * 8);
        qa[r] = q4[0]; qb[r] = q4[1];
        qa[r].x *= C; qa[r].y *= C; qa[r].z *= C; qa[r].w *= C;
        qb[r].x *= C; qb[r].y *= C; qb[r].z *= C; qb[r].w *= C;
    }

    const int k0 = chunk * KEYS_PER_BLOCK + wave * KEYS_PER_WAVE;

    float acc[ROWS][KEYS_PER_WAVE];
    #pragma unroll
    for (int r = 0; r < ROWS; ++r)
        #pragma unroll
        for (int i = 0; i < KEYS_PER_WAVE; ++i)
            acc[r][i] = 0.0f;

    #pragma unroll
    for (int i = 0; i < KEYS_PER_WAVE; ++i) {
        const float4* k4 = reinterpret_cast<const float4*>(keys + (k0 + i) * ND + lane * 8);
        float4 ka = k4[0];
        float4 kb = k4[1];
        // mask once per key element (shared across the 4 rows)
        ka.x = msk(ka.x); ka.y = msk(ka.y); ka.z = msk(ka.z); ka.w = msk(ka.w);
        kb.x = msk(kb.x); kb.y = msk(kb.y); kb.z = msk(kb.z); kb.w = msk(kb.w);
        #pragma unroll
        for (int r = 0; r < ROWS; ++r) {
            float p = acc[r][i];
            p = silu_acc(qa[r].x, ka.x, p);
            p = silu_acc(qa[r].y, ka.y, p);
            p = silu_acc(qa[r].z, ka.z, p);
            p = silu_acc(qa[r].w, ka.w, p);
            p = silu_acc(qb[r].x, kb.x, p);
            p = silu_acc(qb[r].y, kb.y, p);
            p = silu_acc(qb[r].z, kb.z, p);
            p = silu_acc(qb[r].w, kb.w, p);
            acc[r][i] = p;
        }
    }

    // batched butterfly reduce: 16 independent values per step
    #pragma unroll
    for (int off = 32; off > 0; off >>= 1) {
        #pragma unroll
        for (int r = 0; r < ROWS; ++r)
            #pragma unroll
            for (int i = 0; i < KEYS_PER_WAVE; ++i)
                acc[r][i] += __shfl_xor(acc[r][i], off, 64);
    }

    // per-row argmax over this wave's keys (strict >: earliest key wins ties)
    __shared__ unsigned long long win[WAVES_PER_BLOCK][ROWS];
    if (lane == 0) {
        #pragma unroll
        for (int r = 0; r < ROWS; ++r) {
            float best_s = acc[r][0];
            int best_j = 0;
            #pragma unroll
            for (int i = 1; i < KEYS_PER_WAVE; ++i)
                if (acc[r][i] > best_s) { best_s = acc[r][i]; best_j = i; }
            win[wave][r] = pack_win(best_s, k0 + best_j);
        }
    }
    __syncthreads();

    // cross-wave reduce (packed max also resolves index ties to smaller k)
    if (tid < ROWS) {
        const int r = tid;
        unsigned long long p = win[0][r];
        #pragma unroll
        for (int w = 1; w < WAVES_PER_BLOCK; ++w)
            if (win[w][r] > p) p = win[w][r];
        ws[(bg * ROWS + r) * CHUNKS + chunk] = p;
    }
}

__global__ __launch_bounds__(64) void sia_final(const unsigned long long* __restrict__ ws,
                                                const float* __restrict__ values,
                                                float* __restrict__ out) {
    const int b = blockIdx.x;
    const int lane = threadIdx.x;

    unsigned long long p = ws[b * CHUNKS + lane];
    #pragma unroll
    for (int off = 32; off > 0; off >>= 1) {
        unsigned long long o = __shfl_xor(p, off, 64);
        if (o > p) p = o;
    }
    const uint32_t k = ~(uint32_t)(p & 0xFFFFFFFFull);

    // gather winner's values row: 64 lanes x 8 floats
    const float4* v4 = reinterpret_cast<const float4*>(values + (size_t)k * ND) + lane * 2;
    float4* o4 = reinterpret_cast<float4*>(out + b * ND) + lane * 2;
    o4[0] = v4[0];
    o4[1] = v4[1];

    if (lane == 0)
        out[NB * ND + b] = (float)k;   // winner_idx, read back as float32
}

extern "C" void kernel_launch(void* const* d_in, const int* in_sizes, int n_in,
                              void* d_out, int out_size, void* d_ws, size_t ws_size,
                              hipStream_t stream) {
    const float* q      = (const float*)d_in[0];   // [64, 512]
    const float* keys   = (const float*)d_in[1];   // [1024, 512]
    const float* values = (const float*)d_in[2];   // [1024, 512]
    float* out = (float*)d_out;                    // 64*512 values then 64 idx
    unsigned long long* ws = (unsigned long long*)d_ws;

    sia_scores<<<dim3((NB / ROWS) * CHUNKS), dim3(256), 0, stream>>>(q, keys, ws);
    sia_final<<<dim3(NB), dim3(64), 0, stream>>>(ws, values, out);
}